// Round 3
// baseline (348.294 us; speedup 1.0000x reference)
//
#include <hip/hip_runtime.h>
#include <hip/hip_bf16.h>
#include <cmath>

typedef __bf16 bf16;
typedef __bf16 bf16x8 __attribute__((ext_vector_type(8)));
typedef __bf16 bf16x4 __attribute__((ext_vector_type(4)));
typedef float  f32x4  __attribute__((ext_vector_type(4)));

#define B_   2
#define T_   2048
#define D_   1024
#define H_   16
#define DH_  64
#define BT_  (B_ * T_)     // 4096
#define DFF_ (4 * D_)      // 4096

#define GLDS(gp, lp) __builtin_amdgcn_global_load_lds( \
    (const __attribute__((address_space(1))) void*)(gp), \
    (__attribute__((address_space(3))) void*)(lp), 16, 0, 0)
#define VMCNT(n) asm volatile("s_waitcnt vmcnt(" #n ")" ::: "memory")

// ---------------- fp32 -> bf16 convert, 4 elems/thread ----------------
__global__ void cvt_f32_bf16(const float* __restrict__ src, bf16* __restrict__ dst, int n) {
    int i = (blockIdx.x * blockDim.x + threadIdx.x) * 4;
    if (i >= n) return;
    float4 v = *(const float4*)(src + i);
    bf16x4 o;
    o[0] = (bf16)v.x; o[1] = (bf16)v.y; o[2] = (bf16)v.z; o[3] = (bf16)v.w;
    *(bf16x4*)(dst + i) = o;
}

__device__ __forceinline__ float gelu_f(float v) {
    return 0.5f * v * (1.0f + erff(v * 0.70710678118654752f));
}

// ============ 256x256 deep-pipelined GEMM, BK=32, ring-4 LDS, counted vmcnt ======
// C[M,N] = A[M,K] * Bt[N,K]^T.  512 threads = 8 waves (2 Mx4 N), per-wave 128x64.
// EPI 1: bf16 out = gelu(acc + bias)
// EPI 3: QKV split: col < 2048 -> qk rowmajor [M][2048]; col >= 2048 -> vt [B][1024][T_]
template <int EPI>
__global__ __launch_bounds__(512, 2) void gemm256(
    const bf16* __restrict__ A, const bf16* __restrict__ Bt,
    void* __restrict__ outp, void* __restrict__ outp2,
    const float* __restrict__ bias, int M, int N, int K)
{
    __shared__ __align__(16) bf16 As[4][256 * 32];   // 4 ring buffers, 16KB each
    __shared__ __align__(16) bf16 Bs[4][256 * 32];
    const int tid  = threadIdx.x;
    const int lane = tid & 63, w = tid >> 6;
    const int wr = w >> 2, wc = w & 3;
    const int g = lane >> 4, cc = lane & 15;
    const int m0 = blockIdx.y * 256, n0 = blockIdx.x * 256;
    const int NT = K >> 5;

    f32x4 acc[8][4] = {};

    // staging: tile = 256x32 bf16 = 16KB = 1024 chunks of 16B; thread t -> chunks t, t+512
    const int c0 = tid, c1 = tid + 512;
    const bf16* gA0 = A  + (long)(m0 + (c0 >> 2)) * K + ((c0 & 3) << 3);
    const bf16* gA1 = A  + (long)(m0 + (c1 >> 2)) * K + ((c1 & 3) << 3);
    const bf16* gB0 = Bt + (long)(n0 + (c0 >> 2)) * K + ((c0 & 3) << 3);
    const bf16* gB1 = Bt + (long)(n0 + (c1 >> 2)) * K + ((c1 & 3) << 3);

    auto stage = [&](int t) {
        const int buf = t & 3;
        const int k0  = t << 5;
        GLDS(gA0 + k0, &As[buf][c0 * 8]);
        GLDS(gA1 + k0, &As[buf][c1 * 8]);
        GLDS(gB0 + k0, &Bs[buf][c0 * 8]);
        GLDS(gB1 + k0, &Bs[buf][c1 * 8]);
    };

    // prologue: 3 tiles in flight; wait tile 0 (12 outstanding -> 8)
    stage(0); stage(1); stage(2);
    VMCNT(8);
    __syncthreads();

    for (int t = 0; t < NT; ++t) {
        const bf16* Ab = As[t & 3];
        const bf16* Bb = Bs[t & 3];
        if (t + 3 < NT) stage(t + 3);   // issue 3-ahead into buffer freed at t-1

        bf16x8 a8[8], b4[4];
        #pragma unroll
        for (int mi = 0; mi < 8; mi++)
            a8[mi] = *(const bf16x8*)&Ab[(wr * 128 + mi * 16 + cc) * 32 + g * 8];
        #pragma unroll
        for (int ni = 0; ni < 4; ni++)
            b4[ni] = *(const bf16x8*)&Bb[(wc * 64 + ni * 16 + cc) * 32 + g * 8];

        __builtin_amdgcn_s_setprio(1);
        #pragma unroll
        for (int mi = 0; mi < 8; mi++)
            #pragma unroll
            for (int ni = 0; ni < 2; ni++)
                acc[mi][ni] = __builtin_amdgcn_mfma_f32_16x16x32_bf16(a8[mi], b4[ni], acc[mi][ni], 0, 0, 0);
        __builtin_amdgcn_s_setprio(0);
        __syncthreads();                 // phase cadence: 16 MFMA per barrier
        __builtin_amdgcn_s_setprio(1);
        #pragma unroll
        for (int mi = 0; mi < 8; mi++)
            #pragma unroll
            for (int ni = 2; ni < 4; ni++)
                acc[mi][ni] = __builtin_amdgcn_mfma_f32_16x16x32_bf16(a8[mi], b4[ni], acc[mi][ni], 0, 0, 0);
        __builtin_amdgcn_s_setprio(0);

        if (t == NT - 1) break;
        // counted drain: tile t+1 must be landed; keep newest tiles in flight
        if (t < NT - 3)       { VMCNT(8); }
        else if (t == NT - 3) { VMCNT(4); }
        else                  { VMCNT(0); }
        __syncthreads();
    }

    // epilogue: row = m0 + wr*128 + mi*16 + g*4 + r ; col = n0 + wc*64 + ni*16 + cc
    if constexpr (EPI == 3) {
        if (n0 >= 2048) {
            #pragma unroll
            for (int mi = 0; mi < 8; mi++) {
                #pragma unroll
                for (int ni = 0; ni < 4; ni++) {
                    int vcol  = n0 + wc * 64 + ni * 16 + cc - 2048;
                    int grow0 = m0 + wr * 128 + mi * 16 + g * 4;
                    int bb = grow0 >> 11, tt = grow0 & 2047;
                    bf16x4 o;
                    #pragma unroll
                    for (int r = 0; r < 4; r++) o[r] = (bf16)acc[mi][ni][r];
                    *(bf16x4*)&((bf16*)outp2)[((long)bb * 1024 + vcol) * 2048 + tt] = o;
                }
            }
        } else {
            #pragma unroll
            for (int mi = 0; mi < 8; mi++)
                #pragma unroll
                for (int ni = 0; ni < 4; ni++)
                    #pragma unroll
                    for (int r = 0; r < 4; r++) {
                        int grow = m0 + wr * 128 + mi * 16 + g * 4 + r;
                        int gcol = n0 + wc * 64 + ni * 16 + cc;
                        ((bf16*)outp)[(long)grow * 2048 + gcol] = (bf16)acc[mi][ni][r];
                    }
        }
    } else {
        #pragma unroll
        for (int mi = 0; mi < 8; mi++)
            #pragma unroll
            for (int ni = 0; ni < 4; ni++)
                #pragma unroll
                for (int r = 0; r < 4; r++) {
                    int grow = m0 + wr * 128 + mi * 16 + g * 4 + r;
                    int gcol = n0 + wc * 64 + ni * 16 + cc;
                    float v = acc[mi][ni][r] + bias[gcol];
                    ((bf16*)outp)[(long)grow * N + gcol] = (bf16)gelu_f(v);
                }
    }
}

// ---------------- m97-style 128x128 GEMM for FFN2 (N=1024 -> 256 blocks) ----------
// out f32 = acc + bias + resid
__global__ __launch_bounds__(256) void gemm128_ffn2(
    const bf16* __restrict__ A, const bf16* __restrict__ Bt,
    float* __restrict__ outp, const float* __restrict__ bias,
    const float* __restrict__ resid, int M, int N, int K)
{
    __shared__ __align__(16) bf16 As[128 * 32];
    __shared__ __align__(16) bf16 Bs[128 * 32];
    const int tid  = threadIdx.x;
    const int lane = tid & 63;
    const int w    = tid >> 6;
    const int wr   = w >> 1, wc = w & 1;
    const int g    = lane >> 4, cc = lane & 15;
    const int m0   = blockIdx.y * 128, n0 = blockIdx.x * 128;

    f32x4 acc[4][4] = {};

    const int c0 = tid, c1 = tid + 256;
    const bf16* gA0 = A  + (long)(m0 + (c0 >> 2)) * K + ((c0 & 3) << 3);
    const bf16* gA1 = A  + (long)(m0 + (c1 >> 2)) * K + ((c1 & 3) << 3);
    const bf16* gB0 = Bt + (long)(n0 + (c0 >> 2)) * K + ((c0 & 3) << 3);
    const bf16* gB1 = Bt + (long)(n0 + (c1 >> 2)) * K + ((c1 & 3) << 3);
    bf16* lA0 = As + c0 * 8;
    bf16* lA1 = As + c1 * 8;
    bf16* lB0 = Bs + c0 * 8;
    bf16* lB1 = Bs + c1 * 8;

    for (int k0 = 0; k0 < K; k0 += 32) {
        GLDS(gA0 + k0, lA0);
        GLDS(gA1 + k0, lA1);
        GLDS(gB0 + k0, lB0);
        GLDS(gB1 + k0, lB1);
        __syncthreads();

        bf16x8 af[4], bfr[4];
        #pragma unroll
        for (int mi = 0; mi < 4; mi++)
            af[mi] = *(const bf16x8*)&As[(wr * 64 + mi * 16 + cc) * 32 + g * 8];
        #pragma unroll
        for (int ni = 0; ni < 4; ni++)
            bfr[ni] = *(const bf16x8*)&Bs[(wc * 64 + ni * 16 + cc) * 32 + g * 8];
        #pragma unroll
        for (int mi = 0; mi < 4; mi++)
            #pragma unroll
            for (int ni = 0; ni < 4; ni++)
                acc[mi][ni] = __builtin_amdgcn_mfma_f32_16x16x32_bf16(af[mi], bfr[ni], acc[mi][ni], 0, 0, 0);
        __syncthreads();
    }

    #pragma unroll
    for (int mi = 0; mi < 4; mi++)
        #pragma unroll
        for (int ni = 0; ni < 4; ni++)
            #pragma unroll
            for (int r = 0; r < 4; r++) {
                int grow = m0 + wr * 64 + mi * 16 + g * 4 + r;
                int gcol = n0 + wc * 64 + ni * 16 + cc;
                float v = acc[mi][ni][r] + bias[gcol] + resid[(long)grow * N + gcol];
                outp[(long)grow * N + gcol] = v;
            }
}

// ---------------- flash attention: 4 waves/block, 64 q rows, LDS K/V tiles -----
__global__ __launch_bounds__(256) void attn_kernel(
    const bf16* __restrict__ qk, const bf16* __restrict__ vt,
    const float* __restrict__ x, bf16* __restrict__ hout)
{
    __shared__ __align__(16) bf16 Ks[64 * 64];
    __shared__ __align__(16) bf16 Vs[64 * 64];
    __shared__ __align__(16) bf16 Ps[4][16 * 64];
    const int tid  = threadIdx.x;
    const int lane = tid & 63, w = tid >> 6;
    const int g = lane >> 4, cc = lane & 15;
    const int qt = gridDim.x - 1 - blockIdx.x;   // heavy blocks first
    const int hh = blockIdx.y, b = blockIdx.z;
    const int qbase = qt * 64;

    const bf16* qkb   = qk + (long)b * T_ * 2048;
    const bf16* kbase = qkb + 1024 + hh * 64;
    const bf16* vbase = vt + ((long)b * 1024 + hh * 64) * 2048;

    const long rowQ = (long)(qbase + w * 16 + cc) * 2048 + hh * 64;
    bf16x8 qf0 = *(const bf16x8*)&qkb[rowQ + g * 8];
    bf16x8 qf1 = *(const bf16x8*)&qkb[rowQ + 32 + g * 8];

    float m_run[4] = {-INFINITY, -INFINITY, -INFINITY, -INFINITY};
    float l_run[4] = {0.f, 0.f, 0.f, 0.f};
    f32x4 o_acc[4] = {};

    const int c0 = tid, c1 = tid + 256;
    const int r0 = c0 >> 3, s0 = ((c0 & 7) ^ (r0 & 7)) << 3;
    const int r1 = c1 >> 3, s1 = ((c1 & 7) ^ (r1 & 7)) << 3;
    const int x7 = cc & 7;

    for (int kv0 = 0; kv0 <= qbase; kv0 += 64) {
        GLDS(kbase + (long)(kv0 + r0) * 2048 + s0, Ks + c0 * 8);
        GLDS(kbase + (long)(kv0 + r1) * 2048 + s1, Ks + c1 * 8);
        GLDS(vbase + (long)r0 * 2048 + kv0 + s0, Vs + c0 * 8);
        GLDS(vbase + (long)r1 * 2048 + kv0 + s1, Vs + c1 * 8);
        __syncthreads();

        f32x4 sacc[4] = {};
        #pragma unroll
        for (int kt = 0; kt < 4; kt++) {
            bf16x8 kf0 = *(const bf16x8*)&Ks[(kt * 16 + cc) * 64 + ((g ^ x7) << 3)];
            bf16x8 kf1 = *(const bf16x8*)&Ks[(kt * 16 + cc) * 64 + (((4 | g) ^ x7) << 3)];
            sacc[kt] = __builtin_amdgcn_mfma_f32_16x16x32_bf16(qf0, kf0, sacc[kt], 0, 0, 0);
            sacc[kt] = __builtin_amdgcn_mfma_f32_16x16x32_bf16(qf1, kf1, sacc[kt], 0, 0, 0);
        }

        float pmax[4];
        #pragma unroll
        for (int r = 0; r < 4; r++) {
            float a0 = sacc[0][r] * 0.125f, a1 = sacc[1][r] * 0.125f;
            float a2 = sacc[2][r] * 0.125f, a3 = sacc[3][r] * 0.125f;
            if (kv0 == qbase) {
                int q = w * 16 + 4 * g + r;
                if (cc      > q) a0 = -INFINITY;
                if (16 + cc > q) a1 = -INFINITY;
                if (32 + cc > q) a2 = -INFINITY;
                if (48 + cc > q) a3 = -INFINITY;
            }
            sacc[0][r] = a0; sacc[1][r] = a1; sacc[2][r] = a2; sacc[3][r] = a3;
            pmax[r] = fmaxf(fmaxf(a0, a1), fmaxf(a2, a3));
        }
        #pragma unroll
        for (int mk = 1; mk < 16; mk <<= 1)
            #pragma unroll
            for (int r = 0; r < 4; r++)
                pmax[r] = fmaxf(pmax[r], __shfl_xor(pmax[r], mk));

        float alpha[4], rs[4];
        #pragma unroll
        for (int r = 0; r < 4; r++) {
            float mn = fmaxf(m_run[r], pmax[r]);
            alpha[r] = __expf(m_run[r] - mn);
            m_run[r] = mn;
            float p0 = __expf(sacc[0][r] - mn);
            float p1 = __expf(sacc[1][r] - mn);
            float p2 = __expf(sacc[2][r] - mn);
            float p3 = __expf(sacc[3][r] - mn);
            sacc[0][r] = p0; sacc[1][r] = p1; sacc[2][r] = p2; sacc[3][r] = p3;
            rs[r] = (p0 + p1) + (p2 + p3);
        }
        #pragma unroll
        for (int mk = 1; mk < 16; mk <<= 1)
            #pragma unroll
            for (int r = 0; r < 4; r++)
                rs[r] += __shfl_xor(rs[r], mk);
        #pragma unroll
        for (int r = 0; r < 4; r++) l_run[r] = l_run[r] * alpha[r] + rs[r];
        #pragma unroll
        for (int ec = 0; ec < 4; ec++)
            #pragma unroll
            for (int r = 0; r < 4; r++) o_acc[ec][r] *= alpha[r];

        #pragma unroll
        for (int r = 0; r < 4; r++) {
            int qr = 4 * g + r;
            #pragma unroll
            for (int kt = 0; kt < 4; kt++) {
                int seg = (kt << 1) | (cc >> 3);
                Ps[w][qr * 64 + (((seg ^ (qr & 7)) << 3) | x7)] = (bf16)sacc[kt][r];
            }
        }
        bf16x8 pf0 = *(const bf16x8*)&Ps[w][cc * 64 + ((g ^ x7) << 3)];
        bf16x8 pf1 = *(const bf16x8*)&Ps[w][cc * 64 + (((4 | g) ^ x7) << 3)];

        #pragma unroll
        for (int ec = 0; ec < 4; ec++) {
            bf16x8 vf0 = *(const bf16x8*)&Vs[(ec * 16 + cc) * 64 + ((g ^ x7) << 3)];
            bf16x8 vf1 = *(const bf16x8*)&Vs[(ec * 16 + cc) * 64 + (((4 | g) ^ x7) << 3)];
            o_acc[ec] = __builtin_amdgcn_mfma_f32_16x16x32_bf16(pf0, vf0, o_acc[ec], 0, 0, 0);
            o_acc[ec] = __builtin_amdgcn_mfma_f32_16x16x32_bf16(pf1, vf1, o_acc[ec], 0, 0, 0);
        }
        __syncthreads();
    }

    #pragma unroll
    for (int ec = 0; ec < 4; ec++) {
        #pragma unroll
        for (int r = 0; r < 4; r++) {
            long idx = (long)(b * T_ + qbase + w * 16 + 4 * g + r) * D_ + hh * 64 + ec * 16 + cc;
            hout[idx] = (bf16)(x[idx] + o_acc[ec][r] / l_run[r]);
        }
    }
}

// ---------------- launch ----------------
extern "C" void kernel_launch(void* const* d_in, const int* in_sizes, int n_in,
                              void* d_out, int out_size, void* d_ws, size_t ws_size,
                              hipStream_t stream) {
    const float* x  = (const float*)d_in[0];
    const float* wq = (const float*)d_in[2];
    const float* wk = (const float*)d_in[3];
    const float* wv = (const float*)d_in[4];
    const float* w1 = (const float*)d_in[5];
    const float* b1 = (const float*)d_in[6];
    const float* w2 = (const float*)d_in[7];
    const float* b2 = (const float*)d_in[8];
    float* out = (float*)d_out;

    char* ws = (char*)d_ws;
    bf16* xb   = (bf16*)(ws);                  // [4096,1024]   8 MB
    bf16* wall = (bf16*)(ws + (8L  << 20));    // [3072,1024]   6 MB
    bf16* w1b  = (bf16*)(ws + (14L << 20));    // [4096,1024]   8 MB
    bf16* w2b  = (bf16*)(ws + (22L << 20));    // [1024,4096]   8 MB
    bf16* qkb  = (bf16*)(ws + (30L << 20));    // [4096,2048]  16 MB
    bf16* vtb  = (bf16*)(ws + (46L << 20));    // [2,1024,2048] 8 MB
    bf16* hbuf = (bf16*)(ws + (54L << 20));    // [4096,1024]   8 MB
    bf16* abuf = (bf16*)(ws + (62L << 20));    // [4096,4096]  32 MB

    auto cvt = [&](const float* s, bf16* d, int n) {
        cvt_f32_bf16<<<(n / 4 + 255) / 256, 256, 0, stream>>>(s, d, n);
    };
    cvt(x,  xb,              BT_ * D_);
    cvt(wq, wall,            D_ * D_);
    cvt(wk, wall + D_ * D_,  D_ * D_);
    cvt(wv, wall + 2 * D_ * D_, D_ * D_);
    cvt(w1, w1b, DFF_ * D_);
    cvt(w2, w2b, D_ * DFF_);

    // QKV projection: [4096,1024] x [3072,1024]^T -> qk [4096,2048] + vt [2][1024][2048]
    gemm256<3><<<dim3(3 * D_ / 256, BT_ / 256), 512, 0, stream>>>(
        xb, wall, qkb, vtb, nullptr, BT_, 3 * D_, D_);

    // attention + residual: hbuf = x + attn_out
    attn_kernel<<<dim3(T_ / 64, H_, B_), 256, 0, stream>>>(qkb, vtb, x, hbuf);

    // FFN1: gelu(h @ w1^T + b1) -> [4096,4096] bf16
    gemm256<1><<<dim3(DFF_ / 256, BT_ / 256), 512, 0, stream>>>(
        hbuf, w1b, abuf, nullptr, b1, BT_, DFF_, D_);

    // FFN2 + bias + residual x -> out fp32 [4096,1024]
    gemm128_ffn2<<<dim3(D_ / 128, BT_ / 128), 256, 0, stream>>>(
        abuf, w2b, out, b2, x, BT_, D_, DFF_);
}

// Round 4
// 344.176 us; speedup vs baseline: 1.0120x; 1.0120x over previous
//
#include <hip/hip_runtime.h>
#include <hip/hip_bf16.h>
#include <cmath>

typedef __bf16 bf16;
typedef __bf16 bf16x8 __attribute__((ext_vector_type(8)));
typedef __bf16 bf16x4 __attribute__((ext_vector_type(4)));
typedef float  f32x4  __attribute__((ext_vector_type(4)));

#define B_   2
#define T_   2048
#define D_   1024
#define H_   16
#define DH_  64
#define BT_  (B_ * T_)     // 4096
#define DFF_ (4 * D_)      // 4096

#define GLDS(gp, lp) __builtin_amdgcn_global_load_lds( \
    (const __attribute__((address_space(1))) void*)(gp), \
    (__attribute__((address_space(3))) void*)(lp), 16, 0, 0)
#define VMCNT(n) asm volatile("s_waitcnt vmcnt(" #n ")" ::: "memory")

// ---------------- fp32 -> bf16 convert, 4 elems/thread ----------------
__global__ void cvt_f32_bf16(const float* __restrict__ src, bf16* __restrict__ dst, int n) {
    int i = (blockIdx.x * blockDim.x + threadIdx.x) * 4;
    if (i >= n) return;
    float4 v = *(const float4*)(src + i);
    bf16x4 o;
    o[0] = (bf16)v.x; o[1] = (bf16)v.y; o[2] = (bf16)v.z; o[3] = (bf16)v.w;
    *(bf16x4*)(dst + i) = o;
}

__device__ __forceinline__ float gelu_f(float v) {
    return 0.5f * v * (1.0f + erff(v * 0.70710678118654752f));
}

// ============ 256x256 GEMM, BK=32, ring-4 LDS, RAW barriers + counted vmcnt ======
// C[M,N] = A[M,K] * Bt[N,K]^T.  512 threads = 8 waves (2 M x 4 N), per-wave 128x64.
// LDS layout swizzled (T2, rule #21 both-sides): slot (row, seg) holds global
// segment seg ^ ((row>>1)&3); read xor key = (cc>>1)&3 -> 2-way bank access (free).
// EPI 1: bf16 out = gelu(acc + bias)
// EPI 3: QKV split: col < 2048 -> qk rowmajor [M][2048]; col >= 2048 -> vt [B][1024][T_]
template <int EPI>
__global__ __launch_bounds__(512) void gemm256(
    const bf16* __restrict__ A, const bf16* __restrict__ Bt,
    void* __restrict__ outp, void* __restrict__ outp2,
    const float* __restrict__ bias, int M, int N, int K)
{
    __shared__ __align__(16) bf16 As[4][256 * 32];   // 4 ring buffers, 16KB each
    __shared__ __align__(16) bf16 Bs[4][256 * 32];
    const int tid  = threadIdx.x;
    const int lane = tid & 63, w = tid >> 6;
    const int wr = w >> 2, wc = w & 3;
    const int g = lane >> 4, cc = lane & 15;
    const int xk = (cc >> 1) & 3;                    // read-side swizzle key
    const int m0 = blockIdx.y * 256, n0 = blockIdx.x * 256;
    const int NT = K >> 5;

    f32x4 acc[8][4] = {};

    // staging: tile = 256 rows x 32 cols bf16 = 16KB = 1024 chunks of 16B;
    // thread t -> chunks t, t+512. chunk c -> LDS row c>>2, seg c&3 (linear dest);
    // global source column pre-swizzled so that read-side XOR recovers it.
    const int c0 = tid, c1 = tid + 512;
    const int r0 = c0 >> 2, s0e = (((c0 & 3) ^ ((r0 >> 1) & 3)) << 3);
    const int r1 = c1 >> 2, s1e = (((c1 & 3) ^ ((r1 >> 1) & 3)) << 3);
    const bf16* gA0 = A  + (long)(m0 + r0) * K + s0e;
    const bf16* gA1 = A  + (long)(m0 + r1) * K + s1e;
    const bf16* gB0 = Bt + (long)(n0 + r0) * K + s0e;
    const bf16* gB1 = Bt + (long)(n0 + r1) * K + s1e;

    auto stage = [&](int t) {
        const int buf = t & 3;
        const int k0  = t << 5;
        GLDS(gA0 + k0, &As[buf][c0 * 8]);
        GLDS(gA1 + k0, &As[buf][c1 * 8]);
        GLDS(gB0 + k0, &Bs[buf][c0 * 8]);
        GLDS(gB1 + k0, &Bs[buf][c1 * 8]);
    };

    // prologue: 3 tiles in flight; ensure tile 0 landed in EVERY wave, then barrier
    stage(0); stage(1); stage(2);
    VMCNT(8);
    __builtin_amdgcn_s_barrier();

    for (int t = 0; t < NT; ++t) {
        const bf16* Ab = As[t & 3];
        const bf16* Bb = Bs[t & 3];
        if (t + 3 < NT) stage(t + 3);   // overwrites buf[(t-1)&3]: all reads of it
                                        // completed before the barrier we just crossed

        bf16x8 a8[8], b4[4];
        #pragma unroll
        for (int mi = 0; mi < 8; mi++) {
            int row = wr * 128 + mi * 16 + cc;
            a8[mi] = *(const bf16x8*)&Ab[row * 32 + ((g ^ xk) << 3)];
        }
        #pragma unroll
        for (int ni = 0; ni < 4; ni++) {
            int row = wc * 64 + ni * 16 + cc;
            b4[ni] = *(const bf16x8*)&Bb[row * 32 + ((g ^ xk) << 3)];
        }

        __builtin_amdgcn_s_setprio(1);
        #pragma unroll
        for (int mi = 0; mi < 8; mi++)
            #pragma unroll
            for (int ni = 0; ni < 4; ni++)
                acc[mi][ni] = __builtin_amdgcn_mfma_f32_16x16x32_bf16(a8[mi], b4[ni], acc[mi][ni], 0, 0, 0);
        __builtin_amdgcn_s_setprio(0);

        if (t == NT - 1) break;
        // counted drain (never 0 mid-loop): next iter reads buf[t+1]
        if (t < NT - 3)       { VMCNT(8); }   // stages t+2, t+3 stay in flight
        else if (t == NT - 3) { VMCNT(4); }
        else                  { VMCNT(0); }
        __builtin_amdgcn_s_barrier();
    }

    // epilogue: row = m0 + wr*128 + mi*16 + g*4 + r ; col = n0 + wc*64 + ni*16 + cc
    if constexpr (EPI == 3) {
        if (n0 >= 2048) {
            #pragma unroll
            for (int mi = 0; mi < 8; mi++) {
                #pragma unroll
                for (int ni = 0; ni < 4; ni++) {
                    int vcol  = n0 + wc * 64 + ni * 16 + cc - 2048;
                    int grow0 = m0 + wr * 128 + mi * 16 + g * 4;
                    int bb = grow0 >> 11, tt = grow0 & 2047;
                    bf16x4 o;
                    #pragma unroll
                    for (int r = 0; r < 4; r++) o[r] = (bf16)acc[mi][ni][r];
                    *(bf16x4*)&((bf16*)outp2)[((long)bb * 1024 + vcol) * 2048 + tt] = o;
                }
            }
        } else {
            #pragma unroll
            for (int mi = 0; mi < 8; mi++)
                #pragma unroll
                for (int ni = 0; ni < 4; ni++)
                    #pragma unroll
                    for (int r = 0; r < 4; r++) {
                        int grow = m0 + wr * 128 + mi * 16 + g * 4 + r;
                        int gcol = n0 + wc * 64 + ni * 16 + cc;
                        ((bf16*)outp)[(long)grow * 2048 + gcol] = (bf16)acc[mi][ni][r];
                    }
        }
    } else {
        #pragma unroll
        for (int mi = 0; mi < 8; mi++)
            #pragma unroll
            for (int ni = 0; ni < 4; ni++)
                #pragma unroll
                for (int r = 0; r < 4; r++) {
                    int grow = m0 + wr * 128 + mi * 16 + g * 4 + r;
                    int gcol = n0 + wc * 64 + ni * 16 + cc;
                    float v = acc[mi][ni][r] + bias[gcol];
                    ((bf16*)outp)[(long)grow * N + gcol] = (bf16)gelu_f(v);
                }
    }
}

// ---------------- m97-style 128x128 GEMM for FFN2 (proven structure) ----------
// out f32 = acc + bias + resid
__global__ __launch_bounds__(256) void gemm128_ffn2(
    const bf16* __restrict__ A, const bf16* __restrict__ Bt,
    float* __restrict__ outp, const float* __restrict__ bias,
    const float* __restrict__ resid, int M, int N, int K)
{
    __shared__ __align__(16) bf16 As[128 * 32];
    __shared__ __align__(16) bf16 Bs[128 * 32];
    const int tid  = threadIdx.x;
    const int lane = tid & 63;
    const int w    = tid >> 6;
    const int wr   = w >> 1, wc = w & 1;
    const int g    = lane >> 4, cc = lane & 15;
    const int m0   = blockIdx.y * 128, n0 = blockIdx.x * 128;

    f32x4 acc[4][4] = {};

    const int c0 = tid, c1 = tid + 256;
    const bf16* gA0 = A  + (long)(m0 + (c0 >> 2)) * K + ((c0 & 3) << 3);
    const bf16* gA1 = A  + (long)(m0 + (c1 >> 2)) * K + ((c1 & 3) << 3);
    const bf16* gB0 = Bt + (long)(n0 + (c0 >> 2)) * K + ((c0 & 3) << 3);
    const bf16* gB1 = Bt + (long)(n0 + (c1 >> 2)) * K + ((c1 & 3) << 3);
    bf16* lA0 = As + c0 * 8;
    bf16* lA1 = As + c1 * 8;
    bf16* lB0 = Bs + c0 * 8;
    bf16* lB1 = Bs + c1 * 8;

    for (int k0 = 0; k0 < K; k0 += 32) {
        GLDS(gA0 + k0, lA0);
        GLDS(gA1 + k0, lA1);
        GLDS(gB0 + k0, lB0);
        GLDS(gB1 + k0, lB1);
        __syncthreads();

        bf16x8 af[4], bfr[4];
        #pragma unroll
        for (int mi = 0; mi < 4; mi++)
            af[mi] = *(const bf16x8*)&As[(wr * 64 + mi * 16 + cc) * 32 + g * 8];
        #pragma unroll
        for (int ni = 0; ni < 4; ni++)
            bfr[ni] = *(const bf16x8*)&Bs[(wc * 64 + ni * 16 + cc) * 32 + g * 8];
        #pragma unroll
        for (int mi = 0; mi < 4; mi++)
            #pragma unroll
            for (int ni = 0; ni < 4; ni++)
                acc[mi][ni] = __builtin_amdgcn_mfma_f32_16x16x32_bf16(af[mi], bfr[ni], acc[mi][ni], 0, 0, 0);
        __syncthreads();
    }

    #pragma unroll
    for (int mi = 0; mi < 4; mi++)
        #pragma unroll
        for (int ni = 0; ni < 4; ni++)
            #pragma unroll
            for (int r = 0; r < 4; r++) {
                int grow = m0 + wr * 64 + mi * 16 + g * 4 + r;
                int gcol = n0 + wc * 64 + ni * 16 + cc;
                float v = acc[mi][ni][r] + bias[gcol] + resid[(long)grow * N + gcol];
                outp[(long)grow * N + gcol] = v;
            }
}

// ---------------- flash attention: 4 waves/block, 64 q rows, LDS K/V tiles -----
__global__ __launch_bounds__(256) void attn_kernel(
    const bf16* __restrict__ qk, const bf16* __restrict__ vt,
    const float* __restrict__ x, bf16* __restrict__ hout)
{
    __shared__ __align__(16) bf16 Ks[64 * 64];
    __shared__ __align__(16) bf16 Vs[64 * 64];
    __shared__ __align__(16) bf16 Ps[4][16 * 64];
    const int tid  = threadIdx.x;
    const int lane = tid & 63, w = tid >> 6;
    const int g = lane >> 4, cc = lane & 15;
    const int qt = gridDim.x - 1 - blockIdx.x;   // heavy blocks first
    const int hh = blockIdx.y, b = blockIdx.z;
    const int qbase = qt * 64;

    const bf16* qkb   = qk + (long)b * T_ * 2048;
    const bf16* kbase = qkb + 1024 + hh * 64;
    const bf16* vbase = vt + ((long)b * 1024 + hh * 64) * 2048;

    const long rowQ = (long)(qbase + w * 16 + cc) * 2048 + hh * 64;
    bf16x8 qf0 = *(const bf16x8*)&qkb[rowQ + g * 8];
    bf16x8 qf1 = *(const bf16x8*)&qkb[rowQ + 32 + g * 8];

    float m_run[4] = {-INFINITY, -INFINITY, -INFINITY, -INFINITY};
    float l_run[4] = {0.f, 0.f, 0.f, 0.f};
    f32x4 o_acc[4] = {};

    const int c0 = tid, c1 = tid + 256;
    const int r0 = c0 >> 3, s0 = ((c0 & 7) ^ (r0 & 7)) << 3;
    const int r1 = c1 >> 3, s1 = ((c1 & 7) ^ (r1 & 7)) << 3;
    const int x7 = cc & 7;

    for (int kv0 = 0; kv0 <= qbase; kv0 += 64) {
        GLDS(kbase + (long)(kv0 + r0) * 2048 + s0, Ks + c0 * 8);
        GLDS(kbase + (long)(kv0 + r1) * 2048 + s1, Ks + c1 * 8);
        GLDS(vbase + (long)r0 * 2048 + kv0 + s0, Vs + c0 * 8);
        GLDS(vbase + (long)r1 * 2048 + kv0 + s1, Vs + c1 * 8);
        __syncthreads();

        f32x4 sacc[4] = {};
        #pragma unroll
        for (int kt = 0; kt < 4; kt++) {
            bf16x8 kf0 = *(const bf16x8*)&Ks[(kt * 16 + cc) * 64 + ((g ^ x7) << 3)];
            bf16x8 kf1 = *(const bf16x8*)&Ks[(kt * 16 + cc) * 64 + (((4 | g) ^ x7) << 3)];
            sacc[kt] = __builtin_amdgcn_mfma_f32_16x16x32_bf16(qf0, kf0, sacc[kt], 0, 0, 0);
            sacc[kt] = __builtin_amdgcn_mfma_f32_16x16x32_bf16(qf1, kf1, sacc[kt], 0, 0, 0);
        }

        float pmax[4];
        #pragma unroll
        for (int r = 0; r < 4; r++) {
            float a0 = sacc[0][r] * 0.125f, a1 = sacc[1][r] * 0.125f;
            float a2 = sacc[2][r] * 0.125f, a3 = sacc[3][r] * 0.125f;
            if (kv0 == qbase) {
                int q = w * 16 + 4 * g + r;
                if (cc      > q) a0 = -INFINITY;
                if (16 + cc > q) a1 = -INFINITY;
                if (32 + cc > q) a2 = -INFINITY;
                if (48 + cc > q) a3 = -INFINITY;
            }
            sacc[0][r] = a0; sacc[1][r] = a1; sacc[2][r] = a2; sacc[3][r] = a3;
            pmax[r] = fmaxf(fmaxf(a0, a1), fmaxf(a2, a3));
        }
        #pragma unroll
        for (int mk = 1; mk < 16; mk <<= 1)
            #pragma unroll
            for (int r = 0; r < 4; r++)
                pmax[r] = fmaxf(pmax[r], __shfl_xor(pmax[r], mk));

        float alpha[4], rs[4];
        #pragma unroll
        for (int r = 0; r < 4; r++) {
            float mn = fmaxf(m_run[r], pmax[r]);
            alpha[r] = __expf(m_run[r] - mn);
            m_run[r] = mn;
            float p0 = __expf(sacc[0][r] - mn);
            float p1 = __expf(sacc[1][r] - mn);
            float p2 = __expf(sacc[2][r] - mn);
            float p3 = __expf(sacc[3][r] - mn);
            sacc[0][r] = p0; sacc[1][r] = p1; sacc[2][r] = p2; sacc[3][r] = p3;
            rs[r] = (p0 + p1) + (p2 + p3);
        }
        #pragma unroll
        for (int mk = 1; mk < 16; mk <<= 1)
            #pragma unroll
            for (int r = 0; r < 4; r++)
                rs[r] += __shfl_xor(rs[r], mk);
        #pragma unroll
        for (int r = 0; r < 4; r++) l_run[r] = l_run[r] * alpha[r] + rs[r];
        #pragma unroll
        for (int ec = 0; ec < 4; ec++)
            #pragma unroll
            for (int r = 0; r < 4; r++) o_acc[ec][r] *= alpha[r];

        #pragma unroll
        for (int r = 0; r < 4; r++) {
            int qr = 4 * g + r;
            #pragma unroll
            for (int kt = 0; kt < 4; kt++) {
                int seg = (kt << 1) | (cc >> 3);
                Ps[w][qr * 64 + (((seg ^ (qr & 7)) << 3) | x7)] = (bf16)sacc[kt][r];
            }
        }
        bf16x8 pf0 = *(const bf16x8*)&Ps[w][cc * 64 + ((g ^ x7) << 3)];
        bf16x8 pf1 = *(const bf16x8*)&Ps[w][cc * 64 + (((4 | g) ^ x7) << 3)];

        #pragma unroll
        for (int ec = 0; ec < 4; ec++) {
            bf16x8 vf0 = *(const bf16x8*)&Vs[(ec * 16 + cc) * 64 + ((g ^ x7) << 3)];
            bf16x8 vf1 = *(const bf16x8*)&Vs[(ec * 16 + cc) * 64 + (((4 | g) ^ x7) << 3)];
            o_acc[ec] = __builtin_amdgcn_mfma_f32_16x16x32_bf16(pf0, vf0, o_acc[ec], 0, 0, 0);
            o_acc[ec] = __builtin_amdgcn_mfma_f32_16x16x32_bf16(pf1, vf1, o_acc[ec], 0, 0, 0);
        }
        __syncthreads();
    }

    #pragma unroll
    for (int ec = 0; ec < 4; ec++) {
        #pragma unroll
        for (int r = 0; r < 4; r++) {
            long idx = (long)(b * T_ + qbase + w * 16 + 4 * g + r) * D_ + hh * 64 + ec * 16 + cc;
            hout[idx] = (bf16)(x[idx] + o_acc[ec][r] / l_run[r]);
        }
    }
}

// ---------------- launch ----------------
extern "C" void kernel_launch(void* const* d_in, const int* in_sizes, int n_in,
                              void* d_out, int out_size, void* d_ws, size_t ws_size,
                              hipStream_t stream) {
    const float* x  = (const float*)d_in[0];
    const float* wq = (const float*)d_in[2];
    const float* wk = (const float*)d_in[3];
    const float* wv = (const float*)d_in[4];
    const float* w1 = (const float*)d_in[5];
    const float* b1 = (const float*)d_in[6];
    const float* w2 = (const float*)d_in[7];
    const float* b2 = (const float*)d_in[8];
    float* out = (float*)d_out;

    char* ws = (char*)d_ws;
    bf16* xb   = (bf16*)(ws);                  // [4096,1024]   8 MB
    bf16* wall = (bf16*)(ws + (8L  << 20));    // [3072,1024]   6 MB
    bf16* w1b  = (bf16*)(ws + (14L << 20));    // [4096,1024]   8 MB
    bf16* w2b  = (bf16*)(ws + (22L << 20));    // [1024,4096]   8 MB
    bf16* qkb  = (bf16*)(ws + (30L << 20));    // [4096,2048]  16 MB
    bf16* vtb  = (bf16*)(ws + (46L << 20));    // [2,1024,2048] 8 MB
    bf16* hbuf = (bf16*)(ws + (54L << 20));    // [4096,1024]   8 MB
    bf16* abuf = (bf16*)(ws + (62L << 20));    // [4096,4096]  32 MB

    auto cvt = [&](const float* s, bf16* d, int n) {
        cvt_f32_bf16<<<(n / 4 + 255) / 256, 256, 0, stream>>>(s, d, n);
    };
    cvt(x,  xb,              BT_ * D_);
    cvt(wq, wall,            D_ * D_);
    cvt(wk, wall + D_ * D_,  D_ * D_);
    cvt(wv, wall + 2 * D_ * D_, D_ * D_);
    cvt(w1, w1b, DFF_ * D_);
    cvt(w2, w2b, D_ * DFF_);

    // QKV projection: [4096,1024] x [3072,1024]^T -> qk [4096,2048] + vt [2][1024][2048]
    gemm256<3><<<dim3(3 * D_ / 256, BT_ / 256), 512, 0, stream>>>(
        xb, wall, qkb, vtb, nullptr, BT_, 3 * D_, D_);

    // attention + residual: hbuf = x + attn_out
    attn_kernel<<<dim3(T_ / 64, H_, B_), 256, 0, stream>>>(qkb, vtb, x, hbuf);

    // FFN1: gelu(h @ w1^T + b1) -> [4096,4096] bf16
    gemm256<1><<<dim3(DFF_ / 256, BT_ / 256), 512, 0, stream>>>(
        hbuf, w1b, abuf, nullptr, b1, BT_, DFF_, D_);

    // FFN2 + bias + residual x -> out fp32 [4096,1024]
    gemm128_ffn2<<<dim3(D_ / 128, BT_ / 128), 256, 0, stream>>>(
        abuf, w2b, out, b2, x, BT_, D_, DFF_);
}

// Round 5
// 321.229 us; speedup vs baseline: 1.0843x; 1.0714x over previous
//
#include <hip/hip_runtime.h>
#include <hip/hip_bf16.h>
#include <cmath>

typedef __bf16 bf16;
typedef __bf16 bf16x8 __attribute__((ext_vector_type(8)));
typedef __bf16 bf16x4 __attribute__((ext_vector_type(4)));
typedef float  f32x4  __attribute__((ext_vector_type(4)));

#define B_   2
#define T_   2048
#define D_   1024
#define H_   16
#define DH_  64
#define BT_  (B_ * T_)     // 4096
#define DFF_ (4 * D_)      // 4096

#define GLDS(gp, lp) __builtin_amdgcn_global_load_lds( \
    (const __attribute__((address_space(1))) void*)(gp), \
    (__attribute__((address_space(3))) void*)(lp), 16, 0, 0)

// ---------------- fp32 -> bf16 convert, 4 elems/thread ----------------
__global__ void cvt_f32_bf16(const float* __restrict__ src, bf16* __restrict__ dst, int n) {
    int i = (blockIdx.x * blockDim.x + threadIdx.x) * 4;
    if (i >= n) return;
    float4 v = *(const float4*)(src + i);
    bf16x4 o;
    o[0] = (bf16)v.x; o[1] = (bf16)v.y; o[2] = (bf16)v.z; o[3] = (bf16)v.w;
    *(bf16x4*)(dst + i) = o;
}

__device__ __forceinline__ float gelu_f(float v) {
    return 0.5f * v * (1.0f + erff(v * 0.70710678118654752f));
}

// ---------------- GEMM: C[M,N] = A[M,K] * Bt[N,K]^T  (m97-style 128x128, PROVEN) --
// EPI 1: bf16 out = gelu(acc + bias); EPI 2: f32 out = acc + bias + resid
// EPI 3: QKV split: col < 2048 -> qk rowmajor [M][2048]; col >= 2048 -> vt [B][1024][T_]
template <int EPI>
__global__ __launch_bounds__(256) void gemm_bt(
    const bf16* __restrict__ A, const bf16* __restrict__ Bt,
    void* __restrict__ outp, void* __restrict__ outp2, const float* __restrict__ bias,
    const float* __restrict__ resid, int M, int N, int K)
{
    __shared__ __align__(16) bf16 As[128 * 32];
    __shared__ __align__(16) bf16 Bs[128 * 32];
    const int tid  = threadIdx.x;
    const int lane = tid & 63;
    const int w    = tid >> 6;
    const int wr   = w >> 1, wc = w & 1;
    const int g    = lane >> 4, cc = lane & 15;
    const int m0   = blockIdx.y * 128, n0 = blockIdx.x * 128;

    f32x4 acc[4][4] = {};

    const int c0 = tid, c1 = tid + 256;
    const bf16* gA0 = A  + (long)(m0 + (c0 >> 2)) * K + ((c0 & 3) << 3);
    const bf16* gA1 = A  + (long)(m0 + (c1 >> 2)) * K + ((c1 & 3) << 3);
    const bf16* gB0 = Bt + (long)(n0 + (c0 >> 2)) * K + ((c0 & 3) << 3);
    const bf16* gB1 = Bt + (long)(n0 + (c1 >> 2)) * K + ((c1 & 3) << 3);
    bf16* lA0 = As + c0 * 8;
    bf16* lA1 = As + c1 * 8;
    bf16* lB0 = Bs + c0 * 8;
    bf16* lB1 = Bs + c1 * 8;

    for (int k0 = 0; k0 < K; k0 += 32) {
        GLDS(gA0 + k0, lA0);
        GLDS(gA1 + k0, lA1);
        GLDS(gB0 + k0, lB0);
        GLDS(gB1 + k0, lB1);
        __syncthreads();

        bf16x8 af[4], bfr[4];
        #pragma unroll
        for (int mi = 0; mi < 4; mi++)
            af[mi] = *(const bf16x8*)&As[(wr * 64 + mi * 16 + cc) * 32 + g * 8];
        #pragma unroll
        for (int ni = 0; ni < 4; ni++)
            bfr[ni] = *(const bf16x8*)&Bs[(wc * 64 + ni * 16 + cc) * 32 + g * 8];
        #pragma unroll
        for (int mi = 0; mi < 4; mi++)
            #pragma unroll
            for (int ni = 0; ni < 4; ni++)
                acc[mi][ni] = __builtin_amdgcn_mfma_f32_16x16x32_bf16(af[mi], bfr[ni], acc[mi][ni], 0, 0, 0);
        __syncthreads();
    }

    if constexpr (EPI == 3) {
        if (n0 >= 2048) {
            #pragma unroll
            for (int mi = 0; mi < 4; mi++) {
                #pragma unroll
                for (int ni = 0; ni < 4; ni++) {
                    int gcol  = n0 + wc * 64 + ni * 16 + cc - 2048;
                    int grow0 = m0 + wr * 64 + mi * 16 + g * 4;
                    int bb = grow0 >> 11, t = grow0 & 2047;
                    bf16x4 o;
                    #pragma unroll
                    for (int r = 0; r < 4; r++) o[r] = (bf16)acc[mi][ni][r];
                    *(bf16x4*)&((bf16*)outp2)[((long)bb * 1024 + gcol) * 2048 + t] = o;
                }
            }
        } else {
            #pragma unroll
            for (int mi = 0; mi < 4; mi++)
                #pragma unroll
                for (int ni = 0; ni < 4; ni++)
                    #pragma unroll
                    for (int r = 0; r < 4; r++) {
                        int grow = m0 + wr * 64 + mi * 16 + g * 4 + r;
                        int gcol = n0 + wc * 64 + ni * 16 + cc;
                        ((bf16*)outp)[(long)grow * 2048 + gcol] = (bf16)acc[mi][ni][r];
                    }
        }
        return;
    }

    #pragma unroll
    for (int mi = 0; mi < 4; mi++) {
        #pragma unroll
        for (int ni = 0; ni < 4; ni++) {
            #pragma unroll
            for (int r = 0; r < 4; r++) {
                int grow = m0 + wr * 64 + mi * 16 + g * 4 + r;
                int gcol = n0 + wc * 64 + ni * 16 + cc;
                float v = acc[mi][ni][r];
                if constexpr (EPI == 1) {
                    v += bias[gcol];
                    ((bf16*)outp)[(long)grow * N + gcol] = (bf16)gelu_f(v);
                } else {
                    v += bias[gcol] + resid[(long)grow * N + gcol];
                    ((float*)outp)[(long)grow * N + gcol] = v;
                }
            }
        }
    }
}

// ---------------- flash attention v3: KVBLK=128, double-buffered K/V, 1 barrier ---
// qk: [BT][2048] bf16 (Q cols 0:1024, K cols 1024:2048, per-head 64-wide)
// vt: [B][1024][T] bf16 (V transposed)
// hout[bt,d] = x[bt,d] + attn_out
__global__ __launch_bounds__(256) void attn_kernel(
    const bf16* __restrict__ qk, const bf16* __restrict__ vt,
    const float* __restrict__ x, bf16* __restrict__ hout)
{
    __shared__ __align__(16) bf16 Ks[2][128 * 64];   // [kv][e], 16KB each
    __shared__ __align__(16) bf16 Vs[2][64 * 128];   // [e][kv], 16KB each
    __shared__ __align__(16) bf16 Ps[4][16 * 128];   // per-wave P, 4KB each
    const int tid  = threadIdx.x;
    const int lane = tid & 63, w = tid >> 6;
    const int g = lane >> 4, cc = lane & 15;
    const int x7 = cc & 7;
    const int qt = gridDim.x - 1 - blockIdx.x;   // heavy blocks first
    const int hh = blockIdx.y, b = blockIdx.z;
    const int qbase = qt * 64;

    const bf16* qkb   = qk + (long)b * T_ * 2048;
    const bf16* kbase = qkb + 1024 + hh * 64;
    const bf16* vbase = vt + ((long)b * 1024 + hh * 64) * 2048;

    // Q fragment (16 q rows per wave), scale 1/8 folded in (exact pow2 in bf16)
    const long rowQ = (long)(qbase + w * 16 + cc) * 2048 + hh * 64;
    bf16x8 qf0 = *(const bf16x8*)&qkb[rowQ + g * 8];
    bf16x8 qf1 = *(const bf16x8*)&qkb[rowQ + 32 + g * 8];
    #pragma unroll
    for (int j = 0; j < 8; j++) {
        qf0[j] = (bf16)((float)qf0[j] * 0.125f);
        qf1[j] = (bf16)((float)qf1[j] * 0.125f);
    }

    float m_run[4] = {-INFINITY, -INFINITY, -INFINITY, -INFINITY};
    float l_run[4] = {0.f, 0.f, 0.f, 0.f};
    f32x4 o_acc[4] = {};

    const int ntiles = (qbase + 191) >> 7;   // ceil((qbase+64)/128)

    // stage K tile (128x64) and V tile (64x128) for tile i into buf i&1.
    // K: 1024 chunks of 16B: chunk c -> row c>>3, slot c&7, src seg = slot^(row&7).
    // V: 1024 chunks: chunk c -> row c>>4, slot c&15, src seg = (slot&8)|((slot&7)^(row&7)).
    auto stage = [&](int i) {
        const int buf = i & 1;
        const int kv0 = i << 7;
        #pragma unroll
        for (int j = 0; j < 4; j++) {
            int ck = tid + j * 256;
            int kr = ck >> 3;
            int kcol = ((ck & 7) ^ (kr & 7)) << 3;
            GLDS(kbase + (long)(kv0 + kr) * 2048 + kcol, &Ks[buf][ck * 8]);
        }
        #pragma unroll
        for (int j = 0; j < 4; j++) {
            int cv = tid + j * 256;
            int vr = cv >> 4, vs = cv & 15;
            int vseg = (vs & 8) | ((vs & 7) ^ (vr & 7));
            GLDS(vbase + (long)vr * 2048 + kv0 + (vseg << 3), &Vs[buf][cv * 8]);
        }
    };

    stage(0);
    __syncthreads();

    for (int i = 0; i < ntiles; ++i) {
        const int buf = i & 1;
        const int kv0 = i << 7;
        if (i + 1 < ntiles) stage(i + 1);   // prefetch; drained by end-of-iter barrier

        // ---- S[16q x 128kv] = (Q/8) K^T : 16 MFMA ----
        f32x4 sacc[8] = {};
        #pragma unroll
        for (int kt = 0; kt < 8; kt++) {
            const bf16* kp = &Ks[buf][(kt * 16 + cc) * 64];
            bf16x8 kf0 = *(const bf16x8*)&kp[(g ^ x7) << 3];
            bf16x8 kf1 = *(const bf16x8*)&kp[((4 | g) ^ x7) << 3];
            sacc[kt] = __builtin_amdgcn_mfma_f32_16x16x32_bf16(qf0, kf0, sacc[kt], 0, 0, 0);
            sacc[kt] = __builtin_amdgcn_mfma_f32_16x16x32_bf16(qf1, kf1, sacc[kt], 0, 0, 0);
        }

        // ---- causal mask (last tile only) ----
        if (i == ntiles - 1) {
            #pragma unroll
            for (int kt = 0; kt < 8; kt++) {
                int kvg = kv0 + kt * 16 + cc;
                #pragma unroll
                for (int r = 0; r < 4; r++) {
                    int qg = qbase + w * 16 + 4 * g + r;
                    if (kvg > qg) sacc[kt][r] = -INFINITY;
                }
            }
        }

        // ---- row max ----
        float pmax[4];
        #pragma unroll
        for (int r = 0; r < 4; r++) {
            float mv = sacc[0][r];
            #pragma unroll
            for (int kt = 1; kt < 8; kt++) mv = fmaxf(mv, sacc[kt][r]);
            pmax[r] = mv;
        }
        #pragma unroll
        for (int mk = 1; mk < 16; mk <<= 1)
            #pragma unroll
            for (int r = 0; r < 4; r++)
                pmax[r] = fmaxf(pmax[r], __shfl_xor(pmax[r], mk));

        // ---- defer-max (T13): rescale only when max grew > 8 ----
        int ok = 1;
        #pragma unroll
        for (int r = 0; r < 4; r++) ok &= (pmax[r] <= m_run[r] + 8.f) ? 1 : 0;
        if (!__all(ok)) {
            float alpha[4];
            #pragma unroll
            for (int r = 0; r < 4; r++) {
                float mn = fmaxf(m_run[r], pmax[r]);
                alpha[r] = __expf(m_run[r] - mn);
                m_run[r] = mn;
                l_run[r] *= alpha[r];
            }
            #pragma unroll
            for (int ec = 0; ec < 4; ec++)
                #pragma unroll
                for (int r = 0; r < 4; r++) o_acc[ec][r] *= alpha[r];
        }

        // ---- P = exp(S - m), row-sum ----
        float rs[4];
        #pragma unroll
        for (int r = 0; r < 4; r++) {
            float s = 0.f;
            #pragma unroll
            for (int kt = 0; kt < 8; kt++) {
                float p = __expf(sacc[kt][r] - m_run[r]);
                sacc[kt][r] = p;
                s += p;
            }
            rs[r] = s;
        }
        #pragma unroll
        for (int mk = 1; mk < 16; mk <<= 1)
            #pragma unroll
            for (int r = 0; r < 4; r++)
                rs[r] += __shfl_xor(rs[r], mk);
        #pragma unroll
        for (int r = 0; r < 4; r++) l_run[r] += rs[r];

        // ---- P: C-layout -> per-wave swizzled LDS ----
        #pragma unroll
        for (int r = 0; r < 4; r++) {
            int qr = 4 * g + r;
            int key = qr & 7;
            #pragma unroll
            for (int kt = 0; kt < 8; kt++) {
                int seg  = (kt << 1) | (cc >> 3);
                int slot = (seg & 8) | ((seg & 7) ^ key);
                Ps[w][qr * 128 + (slot << 3) + (cc & 7)] = (bf16)sacc[kt][r];
            }
        }

        // ---- O += P V : 16 MFMA ----
        #pragma unroll
        for (int ks = 0; ks < 4; ks++) {
            int s_  = ks * 4 + g;
            int slot = (s_ & 8) | ((s_ & 7) ^ x7);
            bf16x8 pf = *(const bf16x8*)&Ps[w][cc * 128 + (slot << 3)];
            #pragma unroll
            for (int ec = 0; ec < 4; ec++) {
                bf16x8 vf = *(const bf16x8*)&Vs[buf][(ec * 16 + cc) * 128 + (slot << 3)];
                o_acc[ec] = __builtin_amdgcn_mfma_f32_16x16x32_bf16(pf, vf, o_acc[ec], 0, 0, 0);
            }
        }
        __syncthreads();   // drains prefetch (vmcnt0) + protects K/V/P for next iter
    }

    #pragma unroll
    for (int ec = 0; ec < 4; ec++) {
        #pragma unroll
        for (int r = 0; r < 4; r++) {
            long idx = (long)(b * T_ + qbase + w * 16 + 4 * g + r) * D_ + hh * 64 + ec * 16 + cc;
            hout[idx] = (bf16)(x[idx] + o_acc[ec][r] / l_run[r]);
        }
    }
}

// ---------------- launch ----------------
extern "C" void kernel_launch(void* const* d_in, const int* in_sizes, int n_in,
                              void* d_out, int out_size, void* d_ws, size_t ws_size,
                              hipStream_t stream) {
    const float* x  = (const float*)d_in[0];
    const float* wq = (const float*)d_in[2];
    const float* wk = (const float*)d_in[3];
    const float* wv = (const float*)d_in[4];
    const float* w1 = (const float*)d_in[5];
    const float* b1 = (const float*)d_in[6];
    const float* w2 = (const float*)d_in[7];
    const float* b2 = (const float*)d_in[8];
    float* out = (float*)d_out;

    char* ws = (char*)d_ws;
    bf16* xb   = (bf16*)(ws);                  // [4096,1024]   8 MB
    bf16* wall = (bf16*)(ws + (8L  << 20));    // [3072,1024]   6 MB
    bf16* w1b  = (bf16*)(ws + (14L << 20));    // [4096,1024]   8 MB
    bf16* w2b  = (bf16*)(ws + (22L << 20));    // [1024,4096]   8 MB
    bf16* qkb  = (bf16*)(ws + (30L << 20));    // [4096,2048]  16 MB
    bf16* vtb  = (bf16*)(ws + (46L << 20));    // [2,1024,2048] 8 MB
    bf16* hbuf = (bf16*)(ws + (54L << 20));    // [4096,1024]   8 MB
    bf16* abuf = (bf16*)(ws + (62L << 20));    // [4096,4096]  32 MB

    auto cvt = [&](const float* s, bf16* d, int n) {
        cvt_f32_bf16<<<(n / 4 + 255) / 256, 256, 0, stream>>>(s, d, n);
    };
    cvt(x,  xb,              BT_ * D_);
    cvt(wq, wall,            D_ * D_);
    cvt(wk, wall + D_ * D_,  D_ * D_);
    cvt(wv, wall + 2 * D_ * D_, D_ * D_);
    cvt(w1, w1b, DFF_ * D_);
    cvt(w2, w2b, D_ * DFF_);

    // QKV projection: [4096,1024] x [3072,1024]^T -> qk [4096,2048] + vt [2][1024][2048]
    gemm_bt<3><<<dim3(3 * D_ / 128, BT_ / 128), 256, 0, stream>>>(
        xb, wall, qkb, vtb, nullptr, nullptr, BT_, 3 * D_, D_);

    // attention + residual: hbuf = x + attn_out
    attn_kernel<<<dim3(T_ / 64, H_, B_), 256, 0, stream>>>(qkb, vtb, x, hbuf);

    // FFN1: gelu(h @ w1^T + b1) -> [4096,4096] bf16
    gemm_bt<1><<<dim3(DFF_ / 128, BT_ / 128), 256, 0, stream>>>(
        hbuf, w1b, abuf, nullptr, b1, nullptr, BT_, DFF_, D_);

    // FFN2 + bias + residual x -> out fp32 [4096,1024]
    gemm_bt<2><<<dim3(D_ / 128, BT_ / 128), 256, 0, stream>>>(
        abuf, w2b, out, nullptr, b2, x, BT_, D_, DFF_);
}